// Round 2
// 412.153 us; speedup vs baseline: 1.2813x; 1.2813x over previous
//
#include <hip/hip_runtime.h>
#include <math.h>

// TopExpertsRouter on MI355X (gfx950) — two-phase, bit-identical numerics to
// the passing kernel: per-(token,expert) logit = 8 chunks of ascending-512
// fmaf chains (xyzw within float4), chunks summed ascending in finish.
//
// (Resubmission: previous round's bench died at container-acquire level —
// "MI355X container failed twice" — with no compile/test/profiling output.
// Kernel re-audited: addressing bijective & in-bounds, no hang paths.)
//
// Theory (from round-0 counters): the gemm was LDS-issue bound (4x4 tile =
// 1 LDS byte/FLOP -> ~165us of ds_read_b128 pipe time vs 55us fmac floor;
// measured 275us, VALUBusy 31%). New gemm:
//   * 8x8 register tile (BT=128 tokens, 128 threads, 8 tok x 8 exp each)
//     -> LDS instructions per FLOP halved
//   * unpadded [rows][32] LDS tiles + XOR swizzle col4' = d4 ^ (row&7):
//     stride 32 floats => bank-quad = col4' mod 8, so the 8 broadcast rows of
//     every ds_read_b128 hit 8 distinct bank-quads (conflict-free), and the
//     unpadded layout is exactly what global_load_lds requires
//   * staging via __builtin_amdgcn_global_load_lds width=16 with PRE-SWIZZLED
//     per-lane global source col (= (l&7) ^ (l>>3)); LDS dest stays linear
//   * 1024 blocks (128 tiles x 8 chunks), 33.8KB LDS -> 4 blocks/CU so one
//     block's barrier/vmcnt drain hides under the others' fmac streams
// Accumulation order per acc: single ascending fmaf chain over d=0..511 of
// its chunk (16 subtiles x 8 d4 x xyzw) — identical to the 8x64 order before.
// Phase 2 (router_finish) byte-identical to the passing version.

constexpr int D  = 4096;
constexpr int E  = 64;
constexpr int K  = 8;
constexpr int BT = 128;  // tokens per block
constexpr int BK = 32;   // d sub-tile (floats)
constexpr int CS = 132;  // cs[e][token] stride: 132 mod 32 = 4 -> 2-way (free)

typedef const unsigned int __attribute__((address_space(1))) gu32;
typedef unsigned int       __attribute__((address_space(3))) lu32;

__device__ __forceinline__ void gload16(const float* src, float* lds_dst)
{
    __builtin_amdgcn_global_load_lds((gu32*)src, (lu32*)lds_dst, 16, 0, 0);
}

__global__ __launch_bounds__(128, 2) void router_gemm(
    const float* __restrict__ x, const float* __restrict__ W,
    float* __restrict__ partial, int ntok, int dlen, int ntiles)
{
    // [0,16384) xs 128x32 f32 (swizzled), [16384,24576) ws 64x32 (swizzled),
    // whole buffer reused afterwards as cs[64][132] = 33792 B
    __shared__ float smem[8448];

    const int tid   = threadIdx.x;
    const int tile  = blockIdx.x % ntiles;
    const int chunk = blockIdx.x / ntiles;
    const int t0 = tile * BT;
    const int d0 = chunk * dlen;

    // ---- staging map (global_load_lds: linear LDS dest, swizzled source) ----
    const int l   = tid & 63;
    const int wv  = tid >> 6;       // wave 0..1
    const int lr  = l >> 3;         // row within 8-row group
    const int lc  = l & 7;          // col4 this lane WRITES (linear)
    const int swc = lc ^ lr;        // col4 this lane must READ from global

    const float* xgw = x + (size_t)(t0 + wv * 64 + lr) * D + d0 + swc * 4;
    const float* wgw = W + (size_t)(wv * 32 + lr) * D + d0 + swc * 4;
    char* xlds = (char*)smem + wv * 8192;            // wave's 64 x-rows
    char* wlds = (char*)smem + 16384 + wv * 4096;    // wave's 32 w-rows

    // ---- compute map: experts e = tx + 8j, tokens t = ty + 16i ----
    const int tx  = tid & 7;
    const int ty  = tid >> 3;       // 0..15 (wave0: 0..7, wave1: 8..15)
    const int ty7 = ty & 7;
    const char* xrd = (const char*)smem + ty * 128;
    const char* wrd = (const char*)smem + 16384 + tx * 128;

    float acc[8][8];
#pragma unroll
    for (int i = 0; i < 8; ++i)
#pragma unroll
        for (int j = 0; j < 8; ++j) acc[i][j] = 0.f;

    const int nk = dlen / BK;
    for (int k = 0; k < nk; ++k) {
        __syncthreads();   // previous compute done before LDS overwrite
        {
            const float* p = xgw + (size_t)k * BK;
#pragma unroll
            for (int ww = 0; ww < 8; ++ww) {          // 8 rows per inst
                gload16(p, (float*)(xlds + ww * 1024));
                p += (size_t)8 * D;
            }
            const float* q = wgw + (size_t)k * BK;
#pragma unroll
            for (int ww = 0; ww < 4; ++ww) {
                gload16(q, (float*)(wlds + ww * 1024));
                q += (size_t)8 * D;
            }
        }
        __syncthreads();   // drains vmcnt -> staged data visible

#pragma unroll
        for (int d4 = 0; d4 < 8; ++d4) {
            float4 xf[8];
            const int cx = (d4 ^ ty7) * 16;           // swizzled read col
#pragma unroll
            for (int i = 0; i < 8; ++i)               // rows ty+16i: row&7==ty7
                xf[i] = *(const float4*)(xrd + i * 2048 + cx);
            const int cw = (d4 ^ tx) * 16;
#pragma unroll
            for (int j = 0; j < 8; ++j) {             // rows tx+8j: row&7==tx
                const float4 wf = *(const float4*)(wrd + j * 1024 + cw);
#pragma unroll
                for (int i = 0; i < 8; ++i) {
                    float a = acc[i][j];
                    a = fmaf(xf[i].x, wf.x, a);
                    a = fmaf(xf[i].y, wf.y, a);
                    a = fmaf(xf[i].z, wf.z, a);
                    a = fmaf(xf[i].w, wf.w, a);
                    acc[i][j] = a;
                }
            }
        }
    }

    // acc -> LDS transpose -> coalesced 256B partial stores [chunk][e][token]
    __syncthreads();
    float* cs = smem;
#pragma unroll
    for (int j = 0; j < 8; ++j)
#pragma unroll
        for (int i = 0; i < 8; ++i)
            cs[(tx + 8 * j) * CS + (ty + 16 * i)] = acc[i][j];
    __syncthreads();

#pragma unroll
    for (int jj = 0; jj < 32; ++jj) {
        const int e = wv * 32 + jj;
        float* dst = partial + ((size_t)chunk * E + e) * ntok + t0;
        dst[l]      = cs[e * CS + l];
        dst[l + 64] = cs[e * CS + l + 64];
    }
}

template <int NC>
__global__ __launch_bounds__(256) void router_finish(
    const float* __restrict__ partial, float* __restrict__ out, int ntok)
{
    __shared__ float ls[64][E + 4];

    const int tid = threadIdx.x;
    const int t0  = blockIdx.x * 64;
    const int t   = tid & 63;
    const int eg  = tid >> 6;

#pragma unroll
    for (int j = 0; j < 16; ++j) {
        const int e = eg * 16 + j;
        const float* p = partial + (size_t)e * ntok + t0 + t;
        float v = p[0];
#pragma unroll
        for (int c = 1; c < NC; ++c)            // ascending: bit-equal
            v += p[(size_t)c * E * ntok];
        ls[t][e] = v;
    }
    __syncthreads();

    if (tid < 64) {
        const int n = t0 + tid;
        float l[E];
#pragma unroll
        for (int g = 0; g < 16; ++g) {
            const float4 v = *(const float4*)&ls[tid][g * 4];
            l[g * 4 + 0] = v.x; l[g * 4 + 1] = v.y;
            l[g * 4 + 2] = v.z; l[g * 4 + 3] = v.w;
        }

        // ---- identical epilogue to passing rounds ----
        float m = l[0];
#pragma unroll
        for (int e = 1; e < E; ++e) m = fmaxf(m, l[e]);
        float sum = 0.f;
#pragma unroll
        for (int e = 0; e < E; ++e) { l[e] = expf(l[e] - m); sum += l[e]; }
        const float inv = 1.f / sum;
#pragma unroll
        for (int e = 0; e < E; ++e) l[e] *= inv;

        float* probs = out + (size_t)ntok * 2 * K + (size_t)n * E;
#pragma unroll
        for (int g = 0; g < 16; ++g)
            *(float4*)&probs[g * 4] =
                make_float4(l[g * 4], l[g * 4 + 1], l[g * 4 + 2], l[g * 4 + 3]);

        float vals[K];
        int   idxs[K];
        float ts = 0.f;
        for (int k = 0; k < K; ++k) {
            float best = -1.f;
            int   bi   = 0;
#pragma unroll
            for (int e = 0; e < E; ++e)
                if (l[e] > best) { best = l[e]; bi = e; }
            vals[k] = best;
            idxs[k] = bi;
            ts += best;
#pragma unroll
            for (int e = 0; e < E; ++e)
                if (e == bi) l[e] = -1.f;
        }
        const float winv = 1.f / (ts + 1e-9f);

        float* oi = out + (size_t)n * K;
        float* ow = out + (size_t)ntok * K + (size_t)n * K;
#pragma unroll
        for (int k = 0; k < K; ++k) {
            oi[k] = (float)idxs[k];
            ow[k] = vals[k] * winv;
        }
    }
}

extern "C" void kernel_launch(void* const* d_in, const int* in_sizes, int n_in,
                              void* d_out, int out_size, void* d_ws, size_t ws_size,
                              hipStream_t stream)
{
    const float* x = (const float*)d_in[0];
    const float* W = (const float*)d_in[1];
    float* out = (float*)d_out;

    const int ntok = in_sizes[0] / D;  // 16384

    // identical nchunks policy to passing rounds (bit-exactness anchor)
    int nchunks = 8;
    while (nchunks > 1 &&
           (size_t)nchunks * E * (size_t)ntok * sizeof(float) > ws_size)
        nchunks >>= 1;
    const int dlen   = D / nchunks;
    const int ntiles = ntok / BT;

    float* partial = (float*)d_ws;

    hipLaunchKernelGGL(router_gemm, dim3(ntiles * nchunks), dim3(128), 0, stream,
                       x, W, partial, ntok, dlen, ntiles);
    switch (nchunks) {
        case 8:
            hipLaunchKernelGGL(router_finish<8>, dim3(ntok / 64), dim3(256), 0,
                               stream, partial, out, ntok);
            break;
        case 4:
            hipLaunchKernelGGL(router_finish<4>, dim3(ntok / 64), dim3(256), 0,
                               stream, partial, out, ntok);
            break;
        case 2:
            hipLaunchKernelGGL(router_finish<2>, dim3(ntok / 64), dim3(256), 0,
                               stream, partial, out, ntok);
            break;
        default:
            hipLaunchKernelGGL(router_finish<1>, dim3(ntok / 64), dim3(256), 0,
                               stream, partial, out, ntok);
            break;
    }
}